// Round 9
// baseline (270.792 us; speedup 1.0000x reference)
//
#include <hip/hip_runtime.h>

#define NROWS 8192
#define BBND  32
#define CBND  512
#define JQ    1024            // j-range per block (8 slices)
#define NR    16              // rounds of 64j per block
#define ABUFB 8192            // A LDS buffer bytes (64 rows x 128B)

typedef unsigned short u16;
typedef unsigned int   u32;
typedef __bf16 bf16x8 __attribute__((ext_vector_type(8)));
typedef float  f32x4  __attribute__((ext_vector_type(4)));
typedef float  f32x16 __attribute__((ext_vector_type(16)));
typedef u32    u32x4  __attribute__((ext_vector_type(4)));
typedef u32    u32x2  __attribute__((ext_vector_type(2)));

#define ZERO4  (f32x4){0.f,0.f,0.f,0.f}
#define ZERO16 (f32x16){0.f,0.f,0.f,0.f,0.f,0.f,0.f,0.f,0.f,0.f,0.f,0.f,0.f,0.f,0.f,0.f}

// raw barrier: drain LDS ops, keep global loads in flight (no vmcnt drain)
#define BAR asm volatile("s_waitcnt lgkmcnt(0)\n\ts_barrier" ::: "memory")

static __device__ inline u16 f2bf(float f) {
    unsigned u = __builtin_bit_cast(unsigned, f);
    unsigned r = (u + 0x7FFFu + ((u >> 16) & 1u)) >> 16;
    return (u16)r;
}

static __device__ inline float pow14(float base) {
    return __builtin_amdgcn_exp2f(1.4f * __builtin_amdgcn_logf(base));
}

static __device__ inline float adj_eval(float dot, float sij) {
    float x = fabsf(2.f * dot - sij);
    float base = fmaxf(1.f - x * (1.f / 32.f), 0.f);
    return pow14(base);
}

static __device__ inline float sigmoidf_fast(float v) {
    float e = __builtin_amdgcn_exp2f(-1.44269504f * v);
    return 1.f / (1.f + e);
}

static __device__ inline u32 cvtpk(float a, float b) {
    u32 r;
    asm("v_cvt_pk_bf16_f32 %0, %1, %2" : "=v"(r) : "v"(a), "v"(b));
    return r;
}

static __device__ inline f32x4 MFMA16(bf16x8 a, bf16x8 b, f32x4 c) {
    return __builtin_amdgcn_mfma_f32_16x16x32_bf16(a, b, c, 0, 0, 0);
}
static __device__ inline f32x16 MFMA32(bf16x8 a, bf16x8 b, f32x16 c) {
    return __builtin_amdgcn_mfma_f32_32x32x16_bf16(a, b, c, 0, 0, 0);
}

// ---------------- prep: row sums of bbn + bf16 copy ----------------
__global__ __launch_bounds__(256) void k_prep_rows(const float* __restrict__ bbn,
                                                   float* __restrict__ s,
                                                   u16* __restrict__ bbn_bf) {
    int i = blockIdx.x * 256 + threadIdx.x;
    if (i >= NROWS) return;
    const f32x4* row = reinterpret_cast<const f32x4*>(bbn + i * BBND);
    float sum = 0.f;
    u16* dst = bbn_bf + i * BBND;
#pragma unroll
    for (int q = 0; q < 8; ++q) {
        f32x4 v = row[q];
#pragma unroll
        for (int e = 0; e < 4; ++e) {
            sum += v[e];
            dst[q * 4 + e] = f2bf(v[e]);
        }
    }
    s[i] = sum;
}

// ---------------- prep: W transpose -> bf16 ----------------
__global__ __launch_bounds__(256) void k_prep_wt(const float* __restrict__ W,
                                                 u16* __restrict__ WT) {
    int idx = blockIdx.x * 256 + threadIdx.x;   // over 512*512
    int c = idx >> 9, k = idx & 511;
    WT[idx] = f2bf(W[k * CBND + c]);            // WT[c][k]
}

// ---------------- degree: d_i = sum_j adj_ij ; dinv = rsqrt(d+eps) ----------------
__global__ __launch_bounds__(512) void k_deg(const u16* __restrict__ bbn_bf,
                                             const float* __restrict__ s,
                                             float* __restrict__ dinv) {
    __shared__ float part[8][16];
    int ibase = blockIdx.x * 16;
    int tid = threadIdx.x;
    int w = tid >> 6, l = tid & 63, lg = l >> 4, lr = l & 15;

    bf16x8 afrag = *reinterpret_cast<const bf16x8*>(bbn_bf + (ibase + lr) * BBND + lg * 8);
    float si[4];
#pragma unroll
    for (int r = 0; r < 4; ++r) si[r] = s[ibase + lg * 4 + r];

    float dacc[4] = {0.f, 0.f, 0.f, 0.f};
    int j0 = w * (NROWS / 8);
    for (int jt = 0; jt < NROWS / 8; jt += 16) {
        int jb = j0 + jt;
        bf16x8 bfrag = *reinterpret_cast<const bf16x8*>(bbn_bf + (jb + lr) * BBND + lg * 8);
        f32x4 dot = MFMA16(afrag, bfrag, ZERO4);
        float sj = s[jb + lr];
#pragma unroll
        for (int r = 0; r < 4; ++r) dacc[r] += adj_eval(dot[r], si[r] + sj);
    }
#pragma unroll
    for (int off = 1; off < 16; off <<= 1)
#pragma unroll
        for (int r = 0; r < 4; ++r) dacc[r] += __shfl_xor(dacc[r], off, 64);

    if (lr == 0) {
#pragma unroll
        for (int r = 0; r < 4; ++r) part[w][lg * 4 + r] = dacc[r];
    }
    __syncthreads();
    if (tid < 16) {
        float d = 0.f;
#pragma unroll
        for (int q = 0; q < 8; ++q) d += part[q][tid];
        dinv[ibase + tid] = rsqrtf(d + 1e-8f);
    }
}

// ---------------- fc: g_blk[(j>>3)*512 + c][j&7] = dinv_j * (cbn@W + b)[j][c] ----------------
__global__ __launch_bounds__(256) void k_fc(const float* __restrict__ cbn,
                                            const u16* __restrict__ WT,
                                            const float* __restrict__ bvec,
                                            const float* __restrict__ dinv,
                                            u16* __restrict__ g_blk) {
    int bid = blockIdx.x;
    int cb = bid & 7, jb = bid >> 3;
    int tid = threadIdx.x, w = tid >> 6, l = tid & 63, lg = l >> 4, lr = l & 15;
    int crow = cb * 64 + w * 16;
    int jcol = jb * 64;

    f32x4 acc[4];
#pragma unroll
    for (int f = 0; f < 4; ++f) acc[f] = ZERO4;

    for (int k0 = 0; k0 < CBND; k0 += 32) {
        bf16x8 afrag = *reinterpret_cast<const bf16x8*>(WT + (crow + lr) * CBND + k0 + lg * 8);
#pragma unroll
        for (int f = 0; f < 4; ++f) {
            const float* src = cbn + (jcol + f * 16 + lr) * CBND + k0 + lg * 8;
            f32x4 v0 = *reinterpret_cast<const f32x4*>(src);
            f32x4 v1 = *reinterpret_cast<const f32x4*>(src + 4);
            bf16x8 bfrag;
#pragma unroll
            for (int e = 0; e < 4; ++e) { bfrag[e] = (__bf16)v0[e]; bfrag[e + 4] = (__bf16)v1[e]; }
            acc[f] = MFMA16(afrag, bfrag, acc[f]);
        }
    }
#pragma unroll
    for (int f = 0; f < 4; ++f) {
#pragma unroll
        for (int r = 0; r < 4; ++r) {
            int c = crow + lg * 4 + r;
            int j = jcol + f * 16 + lr;
            float val = acc[f][r] + bvec[c];
            g_blk[(((j >> 3) * 512 + c) << 3) + (j & 7)] = f2bf(val * dinv[j]);
        }
    }
}

// ---------------- conv: atomic-accumulate sum_j adj_ij * g[:,j] into out ----------------
// 1024-thread blocks (16 waves), block tile 64i x 512c, JQ=1024 (8 slices),
// 16 rounds of 64j. Acc waves: 2 iw x 8 cw, wave tile 32i x 64c -> 32 AGPR
// (halved; with ~90 VGPR fits 4 waves/SIMD -> 16 waves/CU, 2x round 8).
// Gen: 16 waves each make a 16i x 16j quad of a 64i x 64j A supertile
// (swapped MFMA16 + cvtpk, same per-(i,j) math as rounds 4-8); ONE raw
// barrier per 64j. A rows are 128B: swizzle phys16Bslot = logical ^ (row&7)
// -> b128 reads hit the 4-cycle minimum; gen b64 writes 2-way (free).
// B: register-prefetched from g_blk (coalesced 512B segments), k-order per
// accumulator unchanged (kc0 -> kc1, ascending t) => sums bit-identical.

#define LOADB(T, R) { \
    const char* p = gB + (T) * 32768; \
    R##0 = *reinterpret_cast<const u32x4*>(p); \
    R##1 = *reinterpret_cast<const u32x4*>(p + 512); \
    R##2 = *reinterpret_cast<const u32x4*>(p + 16384); \
    R##3 = *reinterpret_cast<const u32x4*>(p + 16384 + 512); \
}

#define GEN(ST, WB) { \
    int jg = jbase + (ST) * 64 + jq8 * 16; \
    bf16x8 fJ = *reinterpret_cast<const bf16x8*>(bbn_bf + (jg + lr) * BBND + lg * 8); \
    f32x4 sj = *reinterpret_cast<const f32x4*>(s + jg + lg * 4); \
    f32x4 dot = MFMA16(fJ, fragI, ZERO4); \
    u32 p0 = cvtpk(adj_eval(dot[0], si + sj[0]), adj_eval(dot[1], si + sj[1])); \
    u32 p1 = cvtpk(adj_eval(dot[2], si + sj[2]), adj_eval(dot[3], si + sj[3])); \
    *reinterpret_cast<u32x2*>(Ab + (WB) * ABUFB + gw) = (u32x2){p0, p1}; \
}

#define CONVP(RB, AK0, AK1, R) { \
    const char* Ar = Ab + (RB) * ABUFB; \
    bf16x8 ak0 = *reinterpret_cast<const bf16x8*>(Ar + (AK0)); \
    bf16x8 ak1 = *reinterpret_cast<const bf16x8*>(Ar + (AK1)); \
    acc0 = MFMA32(ak0, __builtin_bit_cast(bf16x8, R##0), acc0); \
    acc1 = MFMA32(ak0, __builtin_bit_cast(bf16x8, R##1), acc1); \
    acc0 = MFMA32(ak1, __builtin_bit_cast(bf16x8, R##2), acc0); \
    acc1 = MFMA32(ak1, __builtin_bit_cast(bf16x8, R##3), acc1); \
}

#define EPI(ACC, CT) { \
    _Pragma("unroll") \
    for (int reg = 0; reg < 16; ++reg) { \
        int rowD = (reg & 3) + 8 * (reg >> 2) + 4 * lh; \
        unsafeAtomicAdd(out + (long)(ibase + iw * 32 + rowD) * CBND \
                            + cw * 64 + (CT) * 32 + l31, ACC[reg]); \
    } \
}

__global__ __launch_bounds__(1024, 4) void k_conv(const u16* __restrict__ bbn_bf,
                                                  const float* __restrict__ s,
                                                  const u16* __restrict__ g_blk,
                                                  float* __restrict__ out) {
    __shared__ __align__(16) u16 Alds[2][64 * 64];   // 2 x 8KB supertiles

    int bx = blockIdx.x;
    int jq = bx & 7;                   // XCD x's blocks share one 1MB g j-slice
    int it = bx >> 3;                  // 0..127
    int ibase = it * 64;
    int jbase = jq * JQ;

    int tid = threadIdx.x;
    int w = tid >> 6, l = tid & 63;
    int lr = l & 15, lg = l >> 4, l31 = l & 31, lh = l >> 5;
    int iw = w & 1, cw = w >> 1;       // acc wave tile: 32i x 64c (2x8 waves)
    int iq = w & 3, jq8 = w >> 2;      // gen wave tile: 16i x 16j (4x4 waves)

    // gen hoists
    bf16x8 fragI = *reinterpret_cast<const bf16x8*>(bbn_bf + (ibase + iq * 16 + lr) * BBND + lg * 8);
    float si = s[ibase + iq * 16 + lr];

    char* Ab = (char*)&Alds[0][0];

    // B global base: octet (jbase/8 + T*4 + kc*2 + lh), c = cw*64 (+ct*32) + l31
    const char* gB = (const char*)g_blk + (long)jbase * 1024 + lh * 8192
                   + (cw * 64 + l31) * 16;

    // A-frag reads: row = iw*32 + l31 (128B rows), slot = tpar*4 + kc*2 + lh,
    // phys = slot ^ (row&7)
    int arow = iw * 32 + l31;
    int r7 = arow & 7;
    int abase = arow * 128;
    int a00 = abase + (((0 + lh) ^ r7) << 4);   // tpar0 kc0
    int a01 = abase + (((2 + lh) ^ r7) << 4);   // tpar0 kc1
    int a10 = abase + (((4 + lh) ^ r7) << 4);   // tpar1 kc0
    int a11 = abase + (((6 + lh) ^ r7) << 4);   // tpar1 kc1

    // gen write: row = iq*16+lr, logical slot = jq8*2 + (lg>>1), byte +(lg&1)*8
    int grow = iq * 16 + lr;
    int gw = grow * 128 + (((jq8 * 2 + (lg >> 1)) ^ (grow & 7)) << 4) + (lg & 1) * 8;

    f32x16 acc0 = ZERO16, acc1 = ZERO16;

    u32x4 rA0, rA1, rA2, rA3;
    u32x4 rB0, rB1, rB2, rB3;

    // prologue: supertile 0 into buf0, B(t=0) into rA
    GEN(0, 0);
    LOADB(0, rA);
    BAR;

    for (int st = 0; st < NR; ++st) {
        int rb = st & 1, wb = rb ^ 1;
        LOADB(2 * st + 1, rB);
        if (st + 1 < NR) GEN(st + 1, wb);
        CONVP(rb, a00, a01, rA);
        int tn = (2 * st + 2 < 2 * NR) ? 2 * st + 2 : 2 * NR - 1;  // tail: redundant
        LOADB(tn, rA);
        CONVP(rb, a10, a11, rB);
        BAR;
    }

    EPI(acc0, 0);
    EPI(acc1, 1);
}

// ---------------- sigmoid epilogue: out = sigmoid(dinv_i * out), in place ----------------
__global__ __launch_bounds__(256) void k_sig(const float* __restrict__ dinv,
                                             float* __restrict__ out) {
    int idx = blockIdx.x * 256 + threadIdx.x;   // f32x4 index; 1,048,576 total
    float di = dinv[idx >> 7];
    f32x4 v = *reinterpret_cast<const f32x4*>(out + idx * 4);
#pragma unroll
    for (int e = 0; e < 4; ++e) v[e] = sigmoidf_fast(v[e] * di);
    *reinterpret_cast<f32x4*>(out + idx * 4) = v;
}

extern "C" void kernel_launch(void* const* d_in, const int* in_sizes, int n_in,
                              void* d_out, int out_size, void* d_ws, size_t ws_size,
                              hipStream_t stream) {
    const float* bbn = (const float*)d_in[0];   // [8192,32]
    const float* cbn = (const float*)d_in[1];   // [8192,512]
    const float* W   = (const float*)d_in[2];   // [512,512]
    const float* b   = (const float*)d_in[3];   // [512]
    float* out = (float*)d_out;                 // [8192,512] f32

    char* ws = (char*)d_ws;
    float* s      = (float*)ws;  ws += NROWS * 4;
    float* dinv   = (float*)ws;  ws += NROWS * 4;
    u16* bbn_bf   = (u16*)ws;    ws += NROWS * BBND * 2;
    u16* WT       = (u16*)ws;    ws += CBND * CBND * 2;
    u16* g_blk    = (u16*)ws;    ws += CBND * NROWS * 2;

    hipMemsetAsync(d_out, 0, (size_t)out_size * sizeof(float), stream);
    k_prep_rows<<<NROWS / 256, 256, 0, stream>>>(bbn, s, bbn_bf);
    k_prep_wt<<<(CBND * CBND) / 256, 256, 0, stream>>>(W, WT);
    k_deg<<<NROWS / 16, 512, 0, stream>>>(bbn_bf, s, dinv);
    k_fc<<<(NROWS / 64) * (CBND / 64), 256, 0, stream>>>(cbn, WT, b, dinv, g_blk);
    k_conv<<<(NROWS / 64) * 8, 1024, 0, stream>>>(bbn_bf, s, g_blk, out);
    k_sig<<<(NROWS * CBND / 4) / 256, 256, 0, stream>>>(dinv, out);
}

// Round 10
// 237.019 us; speedup vs baseline: 1.1425x; 1.1425x over previous
//
#include <hip/hip_runtime.h>

#define NROWS 8192
#define BBND  32
#define CBND  512
#define NR    128             // rounds of 64j per block (full j sweep)
#define ABUFB 8192            // A LDS buffer bytes (64 rows x 128B)

typedef unsigned short u16;
typedef unsigned int   u32;
typedef __bf16 bf16x8 __attribute__((ext_vector_type(8)));
typedef float  f32x4  __attribute__((ext_vector_type(4)));
typedef float  f32x16 __attribute__((ext_vector_type(16)));
typedef u32    u32x4  __attribute__((ext_vector_type(4)));
typedef u32    u32x2  __attribute__((ext_vector_type(2)));

#define ZERO4  (f32x4){0.f,0.f,0.f,0.f}
#define ZERO16 (f32x16){0.f,0.f,0.f,0.f,0.f,0.f,0.f,0.f,0.f,0.f,0.f,0.f,0.f,0.f,0.f,0.f}

// raw barrier: drain LDS ops, keep global loads in flight (no vmcnt drain)
#define BAR asm volatile("s_waitcnt lgkmcnt(0)\n\ts_barrier" ::: "memory")

static __device__ inline u16 f2bf(float f) {
    unsigned u = __builtin_bit_cast(unsigned, f);
    unsigned r = (u + 0x7FFFu + ((u >> 16) & 1u)) >> 16;
    return (u16)r;
}

static __device__ inline float pow14(float base) {
    return __builtin_amdgcn_exp2f(1.4f * __builtin_amdgcn_logf(base));
}

static __device__ inline float adj_eval(float dot, float sij) {
    float x = fabsf(2.f * dot - sij);
    float base = fmaxf(1.f - x * (1.f / 32.f), 0.f);
    return pow14(base);
}

static __device__ inline float sigmoidf_fast(float v) {
    float e = __builtin_amdgcn_exp2f(-1.44269504f * v);
    return 1.f / (1.f + e);
}

static __device__ inline u32 cvtpk(float a, float b) {
    u32 r;
    asm("v_cvt_pk_bf16_f32 %0, %1, %2" : "=v"(r) : "v"(a), "v"(b));
    return r;
}

static __device__ inline f32x4 MFMA16(bf16x8 a, bf16x8 b, f32x4 c) {
    return __builtin_amdgcn_mfma_f32_16x16x32_bf16(a, b, c, 0, 0, 0);
}
static __device__ inline f32x16 MFMA32(bf16x8 a, bf16x8 b, f32x16 c) {
    return __builtin_amdgcn_mfma_f32_32x32x16_bf16(a, b, c, 0, 0, 0);
}

// ---------------- prep: row sums of bbn + bf16 copy ----------------
__global__ __launch_bounds__(256) void k_prep_rows(const float* __restrict__ bbn,
                                                   float* __restrict__ s,
                                                   u16* __restrict__ bbn_bf) {
    int i = blockIdx.x * 256 + threadIdx.x;
    if (i >= NROWS) return;
    const f32x4* row = reinterpret_cast<const f32x4*>(bbn + i * BBND);
    float sum = 0.f;
    u16* dst = bbn_bf + i * BBND;
#pragma unroll
    for (int q = 0; q < 8; ++q) {
        f32x4 v = row[q];
#pragma unroll
        for (int e = 0; e < 4; ++e) {
            sum += v[e];
            dst[q * 4 + e] = f2bf(v[e]);
        }
    }
    s[i] = sum;
}

// ---------------- prep: W transpose -> bf16 ----------------
__global__ __launch_bounds__(256) void k_prep_wt(const float* __restrict__ W,
                                                 u16* __restrict__ WT) {
    int idx = blockIdx.x * 256 + threadIdx.x;   // over 512*512
    int c = idx >> 9, k = idx & 511;
    WT[idx] = f2bf(W[k * CBND + c]);            // WT[c][k]
}

// ---------------- degree: d_i = sum_j adj_ij ; dinv = rsqrt(d+eps) ----------------
__global__ __launch_bounds__(512) void k_deg(const u16* __restrict__ bbn_bf,
                                             const float* __restrict__ s,
                                             float* __restrict__ dinv) {
    __shared__ float part[8][16];
    int ibase = blockIdx.x * 16;
    int tid = threadIdx.x;
    int w = tid >> 6, l = tid & 63, lg = l >> 4, lr = l & 15;

    bf16x8 afrag = *reinterpret_cast<const bf16x8*>(bbn_bf + (ibase + lr) * BBND + lg * 8);
    float si[4];
#pragma unroll
    for (int r = 0; r < 4; ++r) si[r] = s[ibase + lg * 4 + r];

    float dacc[4] = {0.f, 0.f, 0.f, 0.f};
    int j0 = w * (NROWS / 8);
    for (int jt = 0; jt < NROWS / 8; jt += 16) {
        int jb = j0 + jt;
        bf16x8 bfrag = *reinterpret_cast<const bf16x8*>(bbn_bf + (jb + lr) * BBND + lg * 8);
        f32x4 dot = MFMA16(afrag, bfrag, ZERO4);
        float sj = s[jb + lr];
#pragma unroll
        for (int r = 0; r < 4; ++r) dacc[r] += adj_eval(dot[r], si[r] + sj);
    }
#pragma unroll
    for (int off = 1; off < 16; off <<= 1)
#pragma unroll
        for (int r = 0; r < 4; ++r) dacc[r] += __shfl_xor(dacc[r], off, 64);

    if (lr == 0) {
#pragma unroll
        for (int r = 0; r < 4; ++r) part[w][lg * 4 + r] = dacc[r];
    }
    __syncthreads();
    if (tid < 16) {
        float d = 0.f;
#pragma unroll
        for (int q = 0; q < 8; ++q) d += part[q][tid];
        dinv[ibase + tid] = rsqrtf(d + 1e-8f);
    }
}

// ---------------- fc: g_blk[(j>>3)*512 + c][j&7] = dinv_j * (cbn@W + b)[j][c] ----------------
__global__ __launch_bounds__(256) void k_fc(const float* __restrict__ cbn,
                                            const u16* __restrict__ WT,
                                            const float* __restrict__ bvec,
                                            const float* __restrict__ dinv,
                                            u16* __restrict__ g_blk) {
    int bid = blockIdx.x;
    int cb = bid & 7, jb = bid >> 3;
    int tid = threadIdx.x, w = tid >> 6, l = tid & 63, lg = l >> 4, lr = l & 15;
    int crow = cb * 64 + w * 16;
    int jcol = jb * 64;

    f32x4 acc[4];
#pragma unroll
    for (int f = 0; f < 4; ++f) acc[f] = ZERO4;

    for (int k0 = 0; k0 < CBND; k0 += 32) {
        bf16x8 afrag = *reinterpret_cast<const bf16x8*>(WT + (crow + lr) * CBND + k0 + lg * 8);
#pragma unroll
        for (int f = 0; f < 4; ++f) {
            const float* src = cbn + (jcol + f * 16 + lr) * CBND + k0 + lg * 8;
            f32x4 v0 = *reinterpret_cast<const f32x4*>(src);
            f32x4 v1 = *reinterpret_cast<const f32x4*>(src + 4);
            bf16x8 bfrag;
#pragma unroll
            for (int e = 0; e < 4; ++e) { bfrag[e] = (__bf16)v0[e]; bfrag[e + 4] = (__bf16)v1[e]; }
            acc[f] = MFMA16(afrag, bfrag, acc[f]);
        }
    }
#pragma unroll
    for (int f = 0; f < 4; ++f) {
#pragma unroll
        for (int r = 0; r < 4; ++r) {
            int c = crow + lg * 4 + r;
            int j = jcol + f * 16 + lr;
            float val = acc[f][r] + bvec[c];
            g_blk[(((j >> 3) * 512 + c) << 3) + (j & 7)] = f2bf(val * dinv[j]);
        }
    }
}

// ---------------- conv: out = sigmoid(dinv_i * sum_j adj_ij * g[:,j]), NO atomics ----------------
// Grid 256 = 128 i-tiles x 2 c-halves; block 512 thr (8 waves), tile 64i x 256c,
// full j sweep (128 rounds of 64j). Each block owns its out tile exclusively:
// plain stores, no memset, sigmoid fused. adj generated twice total (c-split 2).
// Acc waves 2iw x 4cw (32i x 64c, 32 AGPR). Gen: wave quad 16i x 32j (2 units),
// round-9 layouts verbatim (A swizzle phys slot = logical ^ (row&7); g_blk
// octet panels; per-acc k-order kc0->kc1 ascending j => same chains).
// Gen fJ/sj register-prefetched one round ahead; B prefetched one chunk ahead;
// raw lgkmcnt-only barrier keeps global loads in flight.

#define LOADB(T, R) { \
    const char* p = gB + (long)(T) * 32768; \
    R##0 = *reinterpret_cast<const u32x4*>(p); \
    R##1 = *reinterpret_cast<const u32x4*>(p + 512); \
    R##2 = *reinterpret_cast<const u32x4*>(p + 16384); \
    R##3 = *reinterpret_cast<const u32x4*>(p + 16384 + 512); \
}

#define LOADG(ST) { \
    int jg0 = (ST) * 64 + jq8 * 32; \
    gJ0 = *reinterpret_cast<const bf16x8*>(bbn_bf + (jg0 + lr) * BBND + lg * 8); \
    gS0 = *reinterpret_cast<const f32x4*>(s + jg0 + lg * 4); \
    gJ1 = *reinterpret_cast<const bf16x8*>(bbn_bf + (jg0 + 16 + lr) * BBND + lg * 8); \
    gS1 = *reinterpret_cast<const f32x4*>(s + jg0 + 16 + lg * 4); \
}

#define GENC(WB) { \
    f32x4 d0 = MFMA16(gJ0, fragI, ZERO4); \
    f32x4 d1 = MFMA16(gJ1, fragI, ZERO4); \
    u32 p00 = cvtpk(adj_eval(d0[0], si + gS0[0]), adj_eval(d0[1], si + gS0[1])); \
    u32 p01 = cvtpk(adj_eval(d0[2], si + gS0[2]), adj_eval(d0[3], si + gS0[3])); \
    u32 p10 = cvtpk(adj_eval(d1[0], si + gS1[0]), adj_eval(d1[1], si + gS1[1])); \
    u32 p11 = cvtpk(adj_eval(d1[2], si + gS1[2]), adj_eval(d1[3], si + gS1[3])); \
    *reinterpret_cast<u32x2*>(Ab + (WB) * ABUFB + gw0) = (u32x2){p00, p01}; \
    *reinterpret_cast<u32x2*>(Ab + (WB) * ABUFB + gw1) = (u32x2){p10, p11}; \
}

#define CONVP(RB, AK0, AK1, R) { \
    const char* Ar = Ab + (RB) * ABUFB; \
    bf16x8 ak0 = *reinterpret_cast<const bf16x8*>(Ar + (AK0)); \
    bf16x8 ak1 = *reinterpret_cast<const bf16x8*>(Ar + (AK1)); \
    acc0 = MFMA32(ak0, __builtin_bit_cast(bf16x8, R##0), acc0); \
    acc1 = MFMA32(ak0, __builtin_bit_cast(bf16x8, R##1), acc1); \
    acc0 = MFMA32(ak1, __builtin_bit_cast(bf16x8, R##2), acc0); \
    acc1 = MFMA32(ak1, __builtin_bit_cast(bf16x8, R##3), acc1); \
}

#define EPI(ACC, CT) { \
    _Pragma("unroll") \
    for (int q = 0; q < 4; ++q) { \
        f32x4 dv = *reinterpret_cast<const f32x4*>(dinv + ibase + iw * 32 + q * 8 + 4 * lh); \
        _Pragma("unroll") \
        for (int r = 0; r < 4; ++r) { \
            int rowD = q * 8 + 4 * lh + r; \
            out[(long)(ibase + iw * 32 + rowD) * CBND + cbase + cw * 64 + (CT) * 32 + l31] \
                = sigmoidf_fast(ACC[q * 4 + r] * dv[r]); \
        } \
    } \
}

__global__ __launch_bounds__(512, 4) void k_conv(const u16* __restrict__ bbn_bf,
                                                 const float* __restrict__ s,
                                                 const float* __restrict__ dinv,
                                                 const u16* __restrict__ g_blk,
                                                 float* __restrict__ out) {
    __shared__ __align__(16) u16 Alds[2][64 * 64];   // 2 x 8KB supertiles

    int bx = blockIdx.x;
    int ch = bx & 1;                   // c-half
    int it = bx >> 1;                  // 0..127
    int ibase = it * 64;
    int cbase = ch * 256;

    int tid = threadIdx.x;
    int w = tid >> 6, l = tid & 63;
    int lr = l & 15, lg = l >> 4, l31 = l & 31, lh = l >> 5;
    int iw = w & 1, cw = w >> 1;       // acc wave tile: 32i x 64c (2x4 waves)
    int iq = w & 3, jq8 = w >> 2;      // gen wave: 16i x 32j (2 units)

    // gen hoists
    bf16x8 fragI = *reinterpret_cast<const bf16x8*>(bbn_bf + (ibase + iq * 16 + lr) * BBND + lg * 8);
    float si = s[ibase + iq * 16 + lr];

    char* Ab = (char*)&Alds[0][0];

    // B global base: octet (T*4 + lh), c = cbase + cw*64 (+ct*32) + l31
    const char* gB = (const char*)g_blk + lh * 8192
                   + (cbase + cw * 64 + l31) * 16;

    // A-frag reads: row = iw*32 + l31 (128B rows), slot = tpar*4 + kc*2 + lh,
    // phys = slot ^ (row&7)
    int arow = iw * 32 + l31;
    int r7 = arow & 7;
    int abase = arow * 128;
    int a00 = abase + (((0 + lh) ^ r7) << 4);   // tpar0 kc0
    int a01 = abase + (((2 + lh) ^ r7) << 4);   // tpar0 kc1
    int a10 = abase + (((4 + lh) ^ r7) << 4);   // tpar1 kc0
    int a11 = abase + (((6 + lh) ^ r7) << 4);   // tpar1 kc1

    // gen writes: row = iq*16+lr; unit u slot = jq8*4 + u*2 + (lg>>1), byte +(lg&1)*8
    int grow = iq * 16 + lr;
    int gw0 = grow * 128 + (((jq8 * 4 + 0 + (lg >> 1)) ^ (grow & 7)) << 4) + (lg & 1) * 8;
    int gw1 = grow * 128 + (((jq8 * 4 + 2 + (lg >> 1)) ^ (grow & 7)) << 4) + (lg & 1) * 8;

    f32x16 acc0 = ZERO16, acc1 = ZERO16;

    u32x4 rA0, rA1, rA2, rA3;
    u32x4 rB0, rB1, rB2, rB3;
    bf16x8 gJ0, gJ1;
    f32x4 gS0, gS1;

    // prologue: gen inputs 0 -> compute into buf0; prefetch gen inputs 1; B(0)
    LOADG(0);
    GENC(0);
    LOADG(1);
    LOADB(0, rA);
    BAR;

    for (int st = 0; st < NR; ++st) {
        int rb = st & 1, wb = rb ^ 1;
        LOADB(2 * st + 1, rB);
        if (st + 1 < NR) GENC(wb);                       // uses prefetched gJ/gS
        if (st + 2 < NR) LOADG(st + 2);                  // refill gJ/gS
        CONVP(rb, a00, a01, rA);
        int tn = (2 * st + 2 < 2 * NR) ? 2 * st + 2 : 2 * NR - 1;  // tail: redundant
        LOADB(tn, rA);
        CONVP(rb, a10, a11, rB);
        BAR;
    }

    EPI(acc0, 0);
    EPI(acc1, 1);
}

extern "C" void kernel_launch(void* const* d_in, const int* in_sizes, int n_in,
                              void* d_out, int out_size, void* d_ws, size_t ws_size,
                              hipStream_t stream) {
    const float* bbn = (const float*)d_in[0];   // [8192,32]
    const float* cbn = (const float*)d_in[1];   // [8192,512]
    const float* W   = (const float*)d_in[2];   // [512,512]
    const float* b   = (const float*)d_in[3];   // [512]
    float* out = (float*)d_out;                 // [8192,512] f32

    char* ws = (char*)d_ws;
    float* s      = (float*)ws;  ws += NROWS * 4;
    float* dinv   = (float*)ws;  ws += NROWS * 4;
    u16* bbn_bf   = (u16*)ws;    ws += NROWS * BBND * 2;
    u16* WT       = (u16*)ws;    ws += CBND * CBND * 2;
    u16* g_blk    = (u16*)ws;    ws += CBND * NROWS * 2;

    k_prep_rows<<<NROWS / 256, 256, 0, stream>>>(bbn, s, bbn_bf);
    k_prep_wt<<<(CBND * CBND) / 256, 256, 0, stream>>>(W, WT);
    k_deg<<<NROWS / 16, 512, 0, stream>>>(bbn_bf, s, dinv);
    k_fc<<<(NROWS / 64) * (CBND / 64), 256, 0, stream>>>(cbn, WT, b, dinv, g_blk);
    k_conv<<<(NROWS / 64) * 2, 512, 0, stream>>>(bbn_bf, s, dinv, g_blk, out);
}

// Round 11
// 211.765 us; speedup vs baseline: 1.2787x; 1.1193x over previous
//
#include <hip/hip_runtime.h>

#define NROWS 8192
#define BBND  32
#define CBND  512
#define JQ    4096            // j-range per block (2 halves)
#define NR    64              // rounds of 64j per block
#define ABUFB 8192            // A LDS buffer bytes (64 rows x 128B)

typedef unsigned short u16;
typedef unsigned int   u32;
typedef __bf16 bf16x8 __attribute__((ext_vector_type(8)));
typedef float  f32x4  __attribute__((ext_vector_type(4)));
typedef float  f32x16 __attribute__((ext_vector_type(16)));
typedef u32    u32x4  __attribute__((ext_vector_type(4)));
typedef u32    u32x2  __attribute__((ext_vector_type(2)));

#define ZERO4  (f32x4){0.f,0.f,0.f,0.f}
#define ZERO16 (f32x16){0.f,0.f,0.f,0.f,0.f,0.f,0.f,0.f,0.f,0.f,0.f,0.f,0.f,0.f,0.f,0.f}

// raw barrier: drain LDS ops, keep global loads in flight (no vmcnt drain)
#define BAR asm volatile("s_waitcnt lgkmcnt(0)\n\ts_barrier" ::: "memory")

static __device__ inline u16 f2bf(float f) {
    unsigned u = __builtin_bit_cast(unsigned, f);
    unsigned r = (u + 0x7FFFu + ((u >> 16) & 1u)) >> 16;
    return (u16)r;
}

static __device__ inline float pow14(float base) {
    return __builtin_amdgcn_exp2f(1.4f * __builtin_amdgcn_logf(base));
}

static __device__ inline float adj_eval(float dot, float sij) {
    float x = fabsf(2.f * dot - sij);
    float base = fmaxf(1.f - x * (1.f / 32.f), 0.f);
    return pow14(base);
}

static __device__ inline float sigmoidf_fast(float v) {
    float e = __builtin_amdgcn_exp2f(-1.44269504f * v);
    return 1.f / (1.f + e);
}

static __device__ inline u32 cvtpk(float a, float b) {
    u32 r;
    asm("v_cvt_pk_bf16_f32 %0, %1, %2" : "=v"(r) : "v"(a), "v"(b));
    return r;
}

static __device__ inline f32x4 MFMA16(bf16x8 a, bf16x8 b, f32x4 c) {
    return __builtin_amdgcn_mfma_f32_16x16x32_bf16(a, b, c, 0, 0, 0);
}
static __device__ inline f32x16 MFMA32(bf16x8 a, bf16x8 b, f32x16 c) {
    return __builtin_amdgcn_mfma_f32_32x32x16_bf16(a, b, c, 0, 0, 0);
}

// ---------------- prep: row sums of bbn + bf16 copy ----------------
__global__ __launch_bounds__(256) void k_prep_rows(const float* __restrict__ bbn,
                                                   float* __restrict__ s,
                                                   u16* __restrict__ bbn_bf) {
    int i = blockIdx.x * 256 + threadIdx.x;
    if (i >= NROWS) return;
    const f32x4* row = reinterpret_cast<const f32x4*>(bbn + i * BBND);
    float sum = 0.f;
    u16* dst = bbn_bf + i * BBND;
#pragma unroll
    for (int q = 0; q < 8; ++q) {
        f32x4 v = row[q];
#pragma unroll
        for (int e = 0; e < 4; ++e) {
            sum += v[e];
            dst[q * 4 + e] = f2bf(v[e]);
        }
    }
    s[i] = sum;
}

// ---------------- prep: W transpose -> bf16 ----------------
__global__ __launch_bounds__(256) void k_prep_wt(const float* __restrict__ W,
                                                 u16* __restrict__ WT) {
    int idx = blockIdx.x * 256 + threadIdx.x;   // over 512*512
    int c = idx >> 9, k = idx & 511;
    WT[idx] = f2bf(W[k * CBND + c]);            // WT[c][k]
}

// ---------------- degree: d_i = sum_j adj_ij ; dinv = rsqrt(d+eps) ----------------
__global__ __launch_bounds__(512) void k_deg(const u16* __restrict__ bbn_bf,
                                             const float* __restrict__ s,
                                             float* __restrict__ dinv) {
    __shared__ float part[8][16];
    int ibase = blockIdx.x * 16;
    int tid = threadIdx.x;
    int w = tid >> 6, l = tid & 63, lg = l >> 4, lr = l & 15;

    bf16x8 afrag = *reinterpret_cast<const bf16x8*>(bbn_bf + (ibase + lr) * BBND + lg * 8);
    float si[4];
#pragma unroll
    for (int r = 0; r < 4; ++r) si[r] = s[ibase + lg * 4 + r];

    float dacc[4] = {0.f, 0.f, 0.f, 0.f};
    int j0 = w * (NROWS / 8);
    for (int jt = 0; jt < NROWS / 8; jt += 16) {
        int jb = j0 + jt;
        bf16x8 bfrag = *reinterpret_cast<const bf16x8*>(bbn_bf + (jb + lr) * BBND + lg * 8);
        f32x4 dot = MFMA16(afrag, bfrag, ZERO4);
        float sj = s[jb + lr];
#pragma unroll
        for (int r = 0; r < 4; ++r) dacc[r] += adj_eval(dot[r], si[r] + sj);
    }
#pragma unroll
    for (int off = 1; off < 16; off <<= 1)
#pragma unroll
        for (int r = 0; r < 4; ++r) dacc[r] += __shfl_xor(dacc[r], off, 64);

    if (lr == 0) {
#pragma unroll
        for (int r = 0; r < 4; ++r) part[w][lg * 4 + r] = dacc[r];
    }
    __syncthreads();
    if (tid < 16) {
        float d = 0.f;
#pragma unroll
        for (int q = 0; q < 8; ++q) d += part[q][tid];
        dinv[ibase + tid] = rsqrtf(d + 1e-8f);
    }
}

// ---------------- fc: g_blk[(j>>3)*512 + c][j&7] = dinv_j * (cbn@W + b)[j][c] ----------------
// bid remap: cb = bx>>7 so the 128 blocks sharing a cb are consecutive ->
// XCD x always gets jb == x (mod 8) -> its cbn rows (2MB) stay L2-resident
// across all 8 cb phases (was: 8 XCDs each re-fetching the same rows).
__global__ __launch_bounds__(256) void k_fc(const float* __restrict__ cbn,
                                            const u16* __restrict__ WT,
                                            const float* __restrict__ bvec,
                                            const float* __restrict__ dinv,
                                            u16* __restrict__ g_blk) {
    int bid = blockIdx.x;
    int cb = bid >> 7, jb = bid & 127;
    int tid = threadIdx.x, w = tid >> 6, l = tid & 63, lg = l >> 4, lr = l & 15;
    int crow = cb * 64 + w * 16;
    int jcol = jb * 64;

    f32x4 acc[4];
#pragma unroll
    for (int f = 0; f < 4; ++f) acc[f] = ZERO4;

    for (int k0 = 0; k0 < CBND; k0 += 32) {
        bf16x8 afrag = *reinterpret_cast<const bf16x8*>(WT + (crow + lr) * CBND + k0 + lg * 8);
#pragma unroll
        for (int f = 0; f < 4; ++f) {
            const float* src = cbn + (jcol + f * 16 + lr) * CBND + k0 + lg * 8;
            f32x4 v0 = *reinterpret_cast<const f32x4*>(src);
            f32x4 v1 = *reinterpret_cast<const f32x4*>(src + 4);
            bf16x8 bfrag;
#pragma unroll
            for (int e = 0; e < 4; ++e) { bfrag[e] = (__bf16)v0[e]; bfrag[e + 4] = (__bf16)v1[e]; }
            acc[f] = MFMA16(afrag, bfrag, acc[f]);
        }
    }
#pragma unroll
    for (int f = 0; f < 4; ++f) {
#pragma unroll
        for (int r = 0; r < 4; ++r) {
            int c = crow + lg * 4 + r;
            int j = jcol + f * 16 + lr;
            float val = acc[f][r] + bvec[c];
            g_blk[(((j >> 3) * 512 + c) << 3) + (j & 7)] = f2bf(val * dinv[j]);
        }
    }
}

// ---------------- conv: partial sums P[jh] = sum_{j in half} adj_ij * g[:,j] ----------------
// Grid 256 = 128 i-tiles x 2 j-halves (1 block/CU, 16 waves). Block 1024 thr,
// tile 64i x 512c, JQ=4096 (64 rounds of 64j). adj generated exactly ONCE per
// (i,j) (c not split). No atomics: each block plain-stores its 64i x 512c f32
// partial to P[jh]. bx&1 is constant per XCD -> each XCD L2-caches its 4MB
// g j-slice. GEN/LOADB/CONVP/swizzles verbatim from round 9 (proven).

#define LOADB(T, R) { \
    const char* p = gB + (long)(T) * 32768; \
    R##0 = *reinterpret_cast<const u32x4*>(p); \
    R##1 = *reinterpret_cast<const u32x4*>(p + 512); \
    R##2 = *reinterpret_cast<const u32x4*>(p + 16384); \
    R##3 = *reinterpret_cast<const u32x4*>(p + 16384 + 512); \
}

#define GEN(ST, WB) { \
    int jg = jbase + (ST) * 64 + jq8 * 16; \
    bf16x8 fJ = *reinterpret_cast<const bf16x8*>(bbn_bf + (jg + lr) * BBND + lg * 8); \
    f32x4 sj = *reinterpret_cast<const f32x4*>(s + jg + lg * 4); \
    f32x4 dot = MFMA16(fJ, fragI, ZERO4); \
    u32 p0 = cvtpk(adj_eval(dot[0], si + sj[0]), adj_eval(dot[1], si + sj[1])); \
    u32 p1 = cvtpk(adj_eval(dot[2], si + sj[2]), adj_eval(dot[3], si + sj[3])); \
    *reinterpret_cast<u32x2*>(Ab + (WB) * ABUFB + gw) = (u32x2){p0, p1}; \
}

#define CONVP(RB, AK0, AK1, R) { \
    const char* Ar = Ab + (RB) * ABUFB; \
    bf16x8 ak0 = *reinterpret_cast<const bf16x8*>(Ar + (AK0)); \
    bf16x8 ak1 = *reinterpret_cast<const bf16x8*>(Ar + (AK1)); \
    acc0 = MFMA32(ak0, __builtin_bit_cast(bf16x8, R##0), acc0); \
    acc1 = MFMA32(ak0, __builtin_bit_cast(bf16x8, R##1), acc1); \
    acc0 = MFMA32(ak1, __builtin_bit_cast(bf16x8, R##2), acc0); \
    acc1 = MFMA32(ak1, __builtin_bit_cast(bf16x8, R##3), acc1); \
}

#define EPI(ACC, CT) { \
    _Pragma("unroll") \
    for (int reg = 0; reg < 16; ++reg) { \
        int rowD = (reg & 3) + 8 * (reg >> 2) + 4 * lh; \
        Pq[(long)(ibase + iw * 32 + rowD) * CBND + cw * 64 + (CT) * 32 + l31] = ACC[reg]; \
    } \
}

__global__ __launch_bounds__(1024, 4) void k_conv(const u16* __restrict__ bbn_bf,
                                                  const float* __restrict__ s,
                                                  const u16* __restrict__ g_blk,
                                                  float* __restrict__ P) {
    __shared__ __align__(16) u16 Alds[2][64 * 64];   // 2 x 8KB supertiles

    int bx = blockIdx.x;
    int jq = bx & 1;                   // j-half; constant per XCD (stride-8 dispatch)
    int it = bx >> 1;                  // 0..127
    int ibase = it * 64;
    int jbase = jq * JQ;

    int tid = threadIdx.x;
    int w = tid >> 6, l = tid & 63;
    int lr = l & 15, lg = l >> 4, l31 = l & 31, lh = l >> 5;
    int iw = w & 1, cw = w >> 1;       // acc wave tile: 32i x 64c (2x8 waves)
    int iq = w & 3, jq8 = w >> 2;      // gen wave tile: 16i x 16j (4x4 waves)

    // gen hoists
    bf16x8 fragI = *reinterpret_cast<const bf16x8*>(bbn_bf + (ibase + iq * 16 + lr) * BBND + lg * 8);
    float si = s[ibase + iq * 16 + lr];

    char* Ab = (char*)&Alds[0][0];
    float* Pq = P + (long)jq * (NROWS * CBND);

    // B global base: octet (jbase/8 + T*4 + kc*2 + lh), c = cw*64 (+ct*32) + l31
    const char* gB = (const char*)g_blk + (long)jbase * 1024 + lh * 8192
                   + (cw * 64 + l31) * 16;

    // A-frag reads: row = iw*32 + l31 (128B rows), slot = tpar*4 + kc*2 + lh,
    // phys = slot ^ (row&7)
    int arow = iw * 32 + l31;
    int r7 = arow & 7;
    int abase = arow * 128;
    int a00 = abase + (((0 + lh) ^ r7) << 4);   // tpar0 kc0
    int a01 = abase + (((2 + lh) ^ r7) << 4);   // tpar0 kc1
    int a10 = abase + (((4 + lh) ^ r7) << 4);   // tpar1 kc0
    int a11 = abase + (((6 + lh) ^ r7) << 4);   // tpar1 kc1

    // gen write: row = iq*16+lr, logical slot = jq8*2 + (lg>>1), byte +(lg&1)*8
    int grow = iq * 16 + lr;
    int gw = grow * 128 + (((jq8 * 2 + (lg >> 1)) ^ (grow & 7)) << 4) + (lg & 1) * 8;

    f32x16 acc0 = ZERO16, acc1 = ZERO16;

    u32x4 rA0, rA1, rA2, rA3;
    u32x4 rB0, rB1, rB2, rB3;

    // prologue: supertile 0 into buf0, B(t=0) into rA
    GEN(0, 0);
    LOADB(0, rA);
    BAR;

    for (int st = 0; st < NR; ++st) {
        int rb = st & 1, wb = rb ^ 1;
        LOADB(2 * st + 1, rB);
        if (st + 1 < NR) GEN(st + 1, wb);
        CONVP(rb, a00, a01, rA);
        int tn = (2 * st + 2 < 2 * NR) ? 2 * st + 2 : 2 * NR - 1;  // tail: redundant
        LOADB(tn, rA);
        CONVP(rb, a10, a11, rB);
        BAR;
    }

    EPI(acc0, 0);
    EPI(acc1, 1);
}

// ---------------- combine: out = sigmoid(dinv_i * (P0 + P1)) ----------------
__global__ __launch_bounds__(256) void k_comb(const float* __restrict__ dinv,
                                              const float* __restrict__ P,
                                              float* __restrict__ out) {
    int idx = blockIdx.x * 256 + threadIdx.x;   // f32x4 index; 1,048,576 total
    float di = dinv[idx >> 7];
    f32x4 a = *reinterpret_cast<const f32x4*>(P + (long)idx * 4);
    f32x4 b = *reinterpret_cast<const f32x4*>(P + (long)NROWS * CBND + (long)idx * 4);
    f32x4 v;
#pragma unroll
    for (int e = 0; e < 4; ++e) v[e] = sigmoidf_fast((a[e] + b[e]) * di);
    *reinterpret_cast<f32x4*>(out + (long)idx * 4) = v;
}

extern "C" void kernel_launch(void* const* d_in, const int* in_sizes, int n_in,
                              void* d_out, int out_size, void* d_ws, size_t ws_size,
                              hipStream_t stream) {
    const float* bbn = (const float*)d_in[0];   // [8192,32]
    const float* cbn = (const float*)d_in[1];   // [8192,512]
    const float* W   = (const float*)d_in[2];   // [512,512]
    const float* b   = (const float*)d_in[3];   // [512]
    float* out = (float*)d_out;                 // [8192,512] f32

    char* ws = (char*)d_ws;
    float* s      = (float*)ws;  ws += NROWS * 4;
    float* dinv   = (float*)ws;  ws += NROWS * 4;
    u16* bbn_bf   = (u16*)ws;    ws += NROWS * BBND * 2;
    u16* WT       = (u16*)ws;    ws += CBND * CBND * 2;
    u16* g_blk    = (u16*)ws;    ws += (size_t)CBND * NROWS * 2;
    float* P      = (float*)ws;  ws += (size_t)2 * NROWS * CBND * 4;   // 32MB partials

    k_prep_rows<<<NROWS / 256, 256, 0, stream>>>(bbn, s, bbn_bf);
    k_prep_wt<<<(CBND * CBND) / 256, 256, 0, stream>>>(W, WT);
    k_deg<<<NROWS / 16, 512, 0, stream>>>(bbn_bf, s, dinv);
    k_fc<<<(NROWS / 64) * (CBND / 64), 256, 0, stream>>>(cbn, WT, b, dinv, g_blk);
    k_conv<<<(NROWS / 64) * 2, 1024, 0, stream>>>(bbn_bf, s, g_blk, P);
    k_comb<<<(NROWS * CBND / 4) / 256, 256, 0, stream>>>(dinv, P, out);
}